// Round 6
// baseline (443.841 us; speedup 1.0000x reference)
//
#include <hip/hip_runtime.h>
#include <hip/hip_bf16.h>
#include <stdint.h>

// MQA: B=2, S=2048, D=1024, H=16, DH=64. Inputs f32, OUTPUT f32 (reference dtype!).
// r1-r5 post-mortem: output dtype was bf16-written into an f32 buffer -> scrambled
// compare, bit-identical absmax 27328 across 4 disjoint builds. Fixed here.
// Full MFMA pipeline, split bf16 (hi/lo) on score path AND out-proj for margin.

#define B_   2
#define S_   2048
#define D_   1024
#define H_   16
#define DH_  64
#define MTOT (B_ * S_)  // 4096

typedef short bf16x8 __attribute__((ext_vector_type(8)));
typedef float f32x4 __attribute__((ext_vector_type(4)));
typedef short short4v __attribute__((ext_vector_type(4)));

__device__ __forceinline__ short f2bf(float f) {  // RNE f32->bf16
  unsigned u = __float_as_uint(f);
  u += 0x7FFF + ((u >> 16) & 1);
  return (short)(u >> 16);
}
__device__ __forceinline__ float bf2f(short h) {
  return __uint_as_float(((unsigned)(unsigned short)h) << 16);
}
struct bfpair { short hi, lo; };
__device__ __forceinline__ bfpair split2(float x) {
  bfpair p;
  p.hi = f2bf(x);
  p.lo = f2bf(x - bf2f(p.hi));
  return p;
}

__device__ __forceinline__ void glds16(const void* g, void* l) {
  // direct-to-LDS 16B: LDS dest = wave-uniform base + lane*16 (m104)
  __builtin_amdgcn_global_load_lds((const __attribute__((address_space(1))) void*)g,
                                   (__attribute__((address_space(3))) void*)l, 16, 0, 0);
}

// ---------------- f32 -> bf16 convert, hi/lo split where needed ----------------
__global__ __launch_bounds__(256) void cvt_split(
    const float* __restrict__ q, const float* __restrict__ k, const float* __restrict__ v,
    const float* __restrict__ wq, const float* __restrict__ wk, const float* __restrict__ wv,
    const float* __restrict__ wo,
    short* qhi, short* qlo, short* khi, short* klo, short* vb,
    short* wqh, short* wql, short* wkh, short* wkl, short* wvb,
    short* woh, short* wol) {
  const int U0 = 1048576, U1 = 2097152, U2 = 3145728, U3 = 3407872,
            U4 = 3424256, U5 = 3440640, U6 = 3702784;
  for (int u = blockIdx.x * blockDim.x + threadIdx.x; u < U6; u += gridDim.x * blockDim.x) {
    const float* s; short* dh; short* dl; int r;
    if (u < U0)      { s = q;  dh = qhi; dl = qlo; r = u; }
    else if (u < U1) { s = k;  dh = khi; dl = klo; r = u - U0; }
    else if (u < U2) { s = v;  dh = vb;  dl = nullptr; r = u - U1; }
    else if (u < U3) { s = wq; dh = wqh; dl = wql; r = u - U2; }
    else if (u < U4) { s = wk; dh = wkh; dl = wkl; r = u - U3; }
    else if (u < U5) { s = wv; dh = wvb; dl = nullptr; r = u - U4; }
    else             { s = wo; dh = woh; dl = wol; r = u - U5; }
    float4 x = *(const float4*)(s + (size_t)r * 4);
    bfpair p0 = split2(x.x), p1 = split2(x.y), p2 = split2(x.z), p3 = split2(x.w);
    short4v yh, yl;
    yh.x = p0.hi; yh.y = p1.hi; yh.z = p2.hi; yh.w = p3.hi;
    yl.x = p0.lo; yl.y = p1.lo; yl.z = p2.lo; yl.w = p3.lo;
    *(short4v*)(dh + (size_t)r * 4) = yh;
    if (dl) *(short4v*)(dl + (size_t)r * 4) = yl;
  }
}

// ---------------- GEMM  C = (Ah+Al) * (Bh+Bl)^T, f32 acc ----------------
// 64x64 tile, BK=64, 4 waves, 2x2 of 16x16x32 MFMA per wave.
// NPROD=3: acc += ah*bh + ah*bl + al*bh (split).  NPROD=1: ah*bh only.
// MODE 0: store hi/lo split pair (Ch,Cl) row-major.
// MODE 1: single bf16 TRANSPOSED C[n*ldc+m], packed short4.
// MODE 3: f32 row-major to Cf.
template <int NPROD, int MODE>
__global__ __launch_bounds__(256) void gemm3(
    const short* __restrict__ Ah, const short* __restrict__ Al,
    const short* __restrict__ Bh, const short* __restrict__ Bl,
    short* __restrict__ Ch, short* __restrict__ Cl, float* __restrict__ Cf,
    int K, int lda, int ldb, int ldc, float alpha) {
  __shared__ alignas(16) short Ash[4096], Asl[4096], Bsh[4096], Bsl[4096];
  const int tid = threadIdx.x;
  const int lane = tid & 63, w = tid >> 6;
  const int c = lane & 15, g = lane >> 4;
  const int wm = w >> 1, wn = w & 1;
  const int bm = blockIdx.x * 64, bn = blockIdx.y * 64;
  const int sr = lane >> 3;                 // staging row-within-8 (== row&7)
  const int scs = ((lane & 7) ^ sr) * 8;    // pre-swizzled source col (elems)

  f32x4 acc[2][2] = {};
  for (int k0 = 0; k0 < K; k0 += 64) {
    glds16(Ah + (size_t)(bm + w * 8 + sr) * lda + k0 + scs,      Ash + w * 512);
    glds16(Ah + (size_t)(bm + 32 + w * 8 + sr) * lda + k0 + scs, Ash + 2048 + w * 512);
    glds16(Bh + (size_t)(bn + w * 8 + sr) * ldb + k0 + scs,      Bsh + w * 512);
    glds16(Bh + (size_t)(bn + 32 + w * 8 + sr) * ldb + k0 + scs, Bsh + 2048 + w * 512);
    if constexpr (NPROD == 3) {
      glds16(Al + (size_t)(bm + w * 8 + sr) * lda + k0 + scs,      Asl + w * 512);
      glds16(Al + (size_t)(bm + 32 + w * 8 + sr) * lda + k0 + scs, Asl + 2048 + w * 512);
      glds16(Bl + (size_t)(bn + w * 8 + sr) * ldb + k0 + scs,      Bsl + w * 512);
      glds16(Bl + (size_t)(bn + 32 + w * 8 + sr) * ldb + k0 + scs, Bsl + 2048 + w * 512);
    }
    __syncthreads();
#pragma unroll
    for (int kk = 0; kk < 2; ++kk) {
      bf16x8 ah[2], bh[2], al[2], bl[2];
#pragma unroll
      for (int mt = 0; mt < 2; ++mt) {
        int row = wm * 32 + mt * 16 + c;
        int so = row * 64 + (((kk * 4 + g) ^ (row & 7)) * 8);
        ah[mt] = *(const bf16x8*)(Ash + so);
        if constexpr (NPROD == 3) al[mt] = *(const bf16x8*)(Asl + so);
      }
#pragma unroll
      for (int nt = 0; nt < 2; ++nt) {
        int row = wn * 32 + nt * 16 + c;
        int so = row * 64 + (((kk * 4 + g) ^ (row & 7)) * 8);
        bh[nt] = *(const bf16x8*)(Bsh + so);
        if constexpr (NPROD == 3) bl[nt] = *(const bf16x8*)(Bsl + so);
      }
#pragma unroll
      for (int mt = 0; mt < 2; ++mt)
#pragma unroll
        for (int nt = 0; nt < 2; ++nt) {
          acc[mt][nt] = __builtin_amdgcn_mfma_f32_16x16x32_bf16(ah[mt], bh[nt], acc[mt][nt], 0, 0, 0);
          if constexpr (NPROD == 3) {
            acc[mt][nt] = __builtin_amdgcn_mfma_f32_16x16x32_bf16(ah[mt], bl[nt], acc[mt][nt], 0, 0, 0);
            acc[mt][nt] = __builtin_amdgcn_mfma_f32_16x16x32_bf16(al[mt], bh[nt], acc[mt][nt], 0, 0, 0);
          }
        }
    }
    __syncthreads();
  }
#pragma unroll
  for (int mt = 0; mt < 2; ++mt) {
#pragma unroll
    for (int nt = 0; nt < 2; ++nt) {
      if constexpr (MODE == 0) {
#pragma unroll
        for (int r = 0; r < 4; ++r) {
          int m = bm + wm * 32 + mt * 16 + g * 4 + r;  // D: row=(lane>>4)*4+reg (m89)
          int n = bn + wn * 32 + nt * 16 + c;          //    col=lane&15
          bfpair pr = split2(acc[mt][nt][r] * alpha);
          Ch[(size_t)m * ldc + n] = pr.hi;
          Cl[(size_t)m * ldc + n] = pr.lo;
        }
      } else if constexpr (MODE == 1) {
        int n = bn + wn * 32 + nt * 16 + c;
        int m = bm + wm * 32 + mt * 16 + g * 4;
        short4v y;
        y.x = f2bf(acc[mt][nt][0] * alpha);
        y.y = f2bf(acc[mt][nt][1] * alpha);
        y.z = f2bf(acc[mt][nt][2] * alpha);
        y.w = f2bf(acc[mt][nt][3] * alpha);
        *(short4v*)(Ch + (size_t)n * ldc + m) = y;
      } else {  // MODE 3: f32 row-major
#pragma unroll
        for (int r = 0; r < 4; ++r) {
          int m = bm + wm * 32 + mt * 16 + g * 4 + r;
          int n = bn + wn * 32 + nt * 16 + c;
          Cf[(size_t)m * ldc + n] = acc[mt][nt][r] * alpha;
        }
      }
    }
  }
}

// ---------------- flash MQA attention, split-precision QK^T ----------------
// grid (S/64, H, B), 256 thr. Wave w: 16 q-rows. BKV=64, online softmax.
// K/V from global (L2-resident, shared across heads). P via swizzled per-wave LDS.
// ao written as SPLIT bf16 pair (hi/lo) for the split out-proj.
__global__ __launch_bounds__(256) void mqa_attn(
    const short* __restrict__ qph, const short* __restrict__ qpl,
    const short* __restrict__ kph, const short* __restrict__ kpl,
    const short* __restrict__ vt, short* __restrict__ aoh, short* __restrict__ aol) {
  __shared__ alignas(16) short Plds[4 * 16 * 64];
  const int tid = threadIdx.x;
  const int lane = tid & 63, w = tid >> 6;
  const int c = lane & 15, g = lane >> 4;
  const int qt = blockIdx.x, h = blockIdx.y, b = blockIdx.z;
  const int q0 = qt * 64 + w * 16;

  // Q fragments hoisted (qp pre-scaled by 0.125, hi/lo split)
  const size_t qrow = (size_t)(b * S_ + q0 + c) * D_ + h * DH_;
  bf16x8 aqh0 = *(const bf16x8*)(qph + qrow + g * 8);
  bf16x8 aqh1 = *(const bf16x8*)(qph + qrow + 32 + g * 8);
  bf16x8 aql0 = *(const bf16x8*)(qpl + qrow + g * 8);
  bf16x8 aql1 = *(const bf16x8*)(qpl + qrow + 32 + g * 8);

  float m[4], l[4];
  f32x4 o[4] = {};
#pragma unroll
  for (int r = 0; r < 4; ++r) { m[r] = -3.0e38f; l[r] = 0.f; }

  short* pl = Plds + w * 1024;  // per-wave 16x64 P buffer (2KB)
  const short* kphb = kph + (size_t)b * S_ * DH_;
  const short* kplb = kpl + (size_t)b * S_ * DH_;
  const short* vtb = vt + (size_t)b * S_;

  for (int kv = 0; kv < S_; kv += 64) {
    // ---- scores S = Q K^T, split: qh*kh + ql*kh + qh*kl ----
    f32x4 s[4];
#pragma unroll
    for (int nt = 0; nt < 4; ++nt) {
      const size_t koff = (size_t)(kv + nt * 16 + c) * DH_ + g * 8;
      bf16x8 kh0 = *(const bf16x8*)(kphb + koff);
      bf16x8 kh1 = *(const bf16x8*)(kphb + koff + 32);
      bf16x8 kl0 = *(const bf16x8*)(kplb + koff);
      bf16x8 kl1 = *(const bf16x8*)(kplb + koff + 32);
      f32x4 z = {};
      z = __builtin_amdgcn_mfma_f32_16x16x32_bf16(aqh0, kh0, z, 0, 0, 0);
      z = __builtin_amdgcn_mfma_f32_16x16x32_bf16(aqh1, kh1, z, 0, 0, 0);
      z = __builtin_amdgcn_mfma_f32_16x16x32_bf16(aql0, kh0, z, 0, 0, 0);
      z = __builtin_amdgcn_mfma_f32_16x16x32_bf16(aql1, kh1, z, 0, 0, 0);
      z = __builtin_amdgcn_mfma_f32_16x16x32_bf16(aqh0, kl0, z, 0, 0, 0);
      s[nt] = __builtin_amdgcn_mfma_f32_16x16x32_bf16(aqh1, kl1, z, 0, 0, 0);
    }
    // ---- online softmax (rows g*4+r across the 16 lanes of group g) ----
    float mx[4], rs[4], sc[4];
#pragma unroll
    for (int r = 0; r < 4; ++r)
      mx[r] = fmaxf(fmaxf(s[0][r], s[1][r]), fmaxf(s[2][r], s[3][r]));
#pragma unroll
    for (int off = 1; off < 16; off <<= 1)
#pragma unroll
      for (int r = 0; r < 4; ++r) mx[r] = fmaxf(mx[r], __shfl_xor(mx[r], off));
#pragma unroll
    for (int r = 0; r < 4; ++r) {
      float mn = fmaxf(m[r], mx[r]);
      sc[r] = __expf(m[r] - mn);
      m[r] = mn;
    }
#pragma unroll
    for (int nt = 0; nt < 4; ++nt)
#pragma unroll
      for (int r = 0; r < 4; ++r) s[nt][r] = __expf(s[nt][r] - m[r]);
#pragma unroll
    for (int r = 0; r < 4; ++r) rs[r] = (s[0][r] + s[1][r]) + (s[2][r] + s[3][r]);
#pragma unroll
    for (int off = 1; off < 16; off <<= 1)
#pragma unroll
      for (int r = 0; r < 4; ++r) rs[r] += __shfl_xor(rs[r], off);
#pragma unroll
    for (int r = 0; r < 4; ++r) l[r] = l[r] * sc[r] + rs[r];
#pragma unroll
    for (int f = 0; f < 4; ++f)
#pragma unroll
      for (int r = 0; r < 4; ++r) o[f][r] *= sc[r];
    // ---- P -> LDS (bf16, XOR-swizzled rows; same-wave only) ----
#pragma unroll
    for (int nt = 0; nt < 4; ++nt)
#pragma unroll
      for (int r = 0; r < 4; ++r) {
        int row = g * 4 + r, col = nt * 16 + c;
        int off2 = ((row << 7) + (col << 1)) ^ ((row & 7) << 4);
        *(short*)((char*)pl + off2) = f2bf(s[nt][r]);
      }
    asm volatile("s_waitcnt lgkmcnt(0)" ::: "memory");
    __builtin_amdgcn_sched_barrier(0);
    bf16x8 pa[2];
#pragma unroll
    for (int kk = 0; kk < 2; ++kk) {
      int off2 = (c << 7) + ((((kk * 4 + g) ^ (c & 7))) << 4);
      pa[kk] = *(const bf16x8*)((const char*)pl + off2);
    }
    // ---- O += P V  (vt is [DH][B*S]: B-operand contiguous) ----
#pragma unroll
    for (int f = 0; f < 4; ++f) {
      const short* vr = vtb + (size_t)(f * 16 + c) * MTOT + kv + g * 8;
      bf16x8 v0 = *(const bf16x8*)(vr);
      bf16x8 v1 = *(const bf16x8*)(vr + 32);
      o[f] = __builtin_amdgcn_mfma_f32_16x16x32_bf16(pa[0], v0, o[f], 0, 0, 0);
      o[f] = __builtin_amdgcn_mfma_f32_16x16x32_bf16(pa[1], v1, o[f], 0, 0, 0);
    }
  }
  // ---- epilogue: O / l -> ao split hi/lo at [token][h*64+dh] ----
  float inv[4];
#pragma unroll
  for (int r = 0; r < 4; ++r) inv[r] = 1.0f / l[r];
#pragma unroll
  for (int f = 0; f < 4; ++f)
#pragma unroll
    for (int r = 0; r < 4; ++r) {
      int row = b * S_ + q0 + g * 4 + r;
      int col = h * DH_ + f * 16 + c;
      bfpair pr = split2(o[f][r] * inv[r]);
      aoh[(size_t)row * D_ + col] = pr.hi;
      aol[(size_t)row * D_ + col] = pr.lo;
    }
}

// ---------------- launch ----------------
extern "C" void kernel_launch(void* const* d_in, const int* in_sizes, int n_in,
                              void* d_out, int out_size, void* d_ws, size_t ws_size,
                              hipStream_t stream) {
  const float* q  = (const float*)d_in[0];
  const float* k  = (const float*)d_in[1];
  const float* v  = (const float*)d_in[2];
  const float* wq = (const float*)d_in[3];
  const float* wk = (const float*)d_in[4];
  const float* wv = (const float*)d_in[5];
  const float* wo = (const float*)d_in[6];

  short* p = (short*)d_ws;
  short* qhi = p; p += 4194304;   // dead after Q-proj; reused as aoh
  short* qlo = p; p += 4194304;   // dead after Q-proj; reused as aol
  short* khi = p; p += 4194304;
  short* klo = p; p += 4194304;
  short* vb  = p; p += 4194304;
  short* wqh = p; p += 1048576;
  short* wql = p; p += 1048576;
  short* wkh = p; p += 65536;
  short* wkl = p; p += 65536;
  short* wvb = p; p += 65536;
  short* woh = p; p += 1048576;
  short* wol = p; p += 1048576;
  short* qph = p; p += 4194304;
  short* qpl = p; p += 4194304;
  short* kph = p; p += 262144;
  short* kpl = p; p += 262144;
  short* vt  = p; p += 262144;
  short* aoh = qhi;               // alias (stream-ordered reuse)
  short* aol = qlo;
  // total ~69.1 MB

  cvt_split<<<dim3(2048), dim3(256), 0, stream>>>(q, k, v, wq, wk, wv, wo,
      qhi, qlo, khi, klo, vb, wqh, wql, wkh, wkl, wvb, woh, wol);
  // qp = q @ wq^T * 0.125 (split)
  gemm3<3, 0><<<dim3(64, 16), dim3(256), 0, stream>>>(qhi, qlo, wqh, wql, qph, qpl,
      nullptr, 1024, 1024, 1024, 1024, 0.125f);
  // kp = k @ wk^T (split)
  gemm3<3, 0><<<dim3(64, 1), dim3(256), 0, stream>>>(khi, klo, wkh, wkl, kph, kpl,
      nullptr, 1024, 1024, 1024, 64, 1.0f);
  // vt = (v @ wv^T)^T (single bf16)
  gemm3<1, 1><<<dim3(64, 1), dim3(256), 0, stream>>>(vb, nullptr, wvb, nullptr, vt,
      nullptr, nullptr, 1024, 1024, 1024, 4096, 1.0f);
  // attention -> ao split
  mqa_attn<<<dim3(32, 16, 2), dim3(256), 0, stream>>>(qph, qpl, kph, kpl, vt, aoh, aol);
  // d_out(f32) = ao @ wo^T (split x split, f32 store)
  gemm3<3, 3><<<dim3(64, 16), dim3(256), 0, stream>>>(aoh, aol, woh, wol, nullptr,
      nullptr, (float*)d_out, 1024, 1024, 1024, 1024, 1.0f);
}